// Round 14
// baseline (317.015 us; speedup 1.0000x reference)
//
#include <hip/hip_runtime.h>
#include <stdint.h>

// H-maxima: 128 iters of m = min(dilate3x3(m), img), marker0 = img - h.
// 4 launches x 32 register-resident iterations, fp16 packed (2 px/word).
// R13-proven structure (W8 named-field state, h2 elementwise, alignb, DPP,
// LDS [2][65][132] = 68.6 KB, seg*8, two barriers/iter).
// NEW vs R13: amdgpu_waves_per_eu(4,4) pins exactly 4 waves/SIMD ->
// 128-VGPR budget for our 16-wave/1-block-per-CU dispatch (compiler was
// capping at 40 VGPR for an unreachable 2-block occupancy -> 2.6x spill bloat).

#define NEGPAIR 0xFBFFFBFFu   // fp16 -65504 x2 == -inf pad
#define TITER 32
#define GROUPS 64
#define LDSS 132              // row stride in words (proven)

typedef _Float16 h2  __attribute__((ext_vector_type(2)));
typedef __fp16   fh2 __attribute__((ext_vector_type(2)));

static __device__ __forceinline__ uint32_t pmax(uint32_t a, uint32_t b) {
    h2 r = __builtin_elementwise_max(__builtin_bit_cast(h2, a), __builtin_bit_cast(h2, b));
    return __builtin_bit_cast(uint32_t, r);
}
static __device__ __forceinline__ uint32_t pmin(uint32_t a, uint32_t b) {
    h2 r = __builtin_elementwise_min(__builtin_bit_cast(h2, a), __builtin_bit_cast(h2, b));
    return __builtin_bit_cast(uint32_t, r);
}
static __device__ __forceinline__ uint32_t alignb(uint32_t hi, uint32_t lo) {
    return __builtin_amdgcn_alignbit(hi, lo, 16);   // {lo.hi16, hi.lo16}
}
static __device__ __forceinline__ uint32_t pack2(float lo, float hi) {
    fh2 p = __builtin_amdgcn_cvt_pkrtz(lo, hi);
    return __builtin_bit_cast(uint32_t, p);
}
// seg s gets seg s-1's word; seg 0 gets NEGPAIR (16-lane DPP row == seg group)
static __device__ __forceinline__ uint32_t dpp_shr1(uint32_t s) {
    return (uint32_t)__builtin_amdgcn_update_dpp((int)NEGPAIR, (int)s, 0x111, 0xF, 0xF, false);
}
// seg s gets seg s+1's word; seg 15 gets NEGPAIR
static __device__ __forceinline__ uint32_t dpp_shl1(uint32_t s) {
    return (uint32_t)__builtin_amdgcn_update_dpp((int)NEGPAIR, (int)s, 0x101, 0xF, 0xF, false);
}

struct W8 { uint32_t s0, s1, s2, s3, s4, s5, s6, s7; };

static __device__ __forceinline__ W8 ld8(const uint32_t* p) {
    uint4 a = reinterpret_cast<const uint4*>(p)[0];
    uint4 b = reinterpret_cast<const uint4*>(p)[1];
    W8 w;
    w.s0 = a.x; w.s1 = a.y; w.s2 = a.z; w.s3 = a.w;
    w.s4 = b.x; w.s5 = b.y; w.s6 = b.z; w.s7 = b.w;
    return w;
}
static __device__ __forceinline__ void st8(uint32_t* p, W8 w) {
    reinterpret_cast<uint4*>(p)[0] = make_uint4(w.s0, w.s1, w.s2, w.s3);
    reinterpret_cast<uint4*>(p)[1] = make_uint4(w.s4, w.s5, w.s6, w.s7);
}
static __device__ __forceinline__ W8 wmax(W8 a, W8 b) {
    W8 r;
    r.s0 = pmax(a.s0, b.s0); r.s1 = pmax(a.s1, b.s1);
    r.s2 = pmax(a.s2, b.s2); r.s3 = pmax(a.s3, b.s3);
    r.s4 = pmax(a.s4, b.s4); r.s5 = pmax(a.s5, b.s5);
    r.s6 = pmax(a.s6, b.s6); r.s7 = pmax(a.s7, b.s7);
    return r;
}
static __device__ __forceinline__ W8 wneg() {
    W8 r;
    r.s0 = NEGPAIR; r.s1 = NEGPAIR; r.s2 = NEGPAIR; r.s3 = NEGPAIR;
    r.s4 = NEGPAIR; r.s5 = NEGPAIR; r.s6 = NEGPAIR; r.s7 = NEGPAIR;
    return r;
}

// horizontal 3-tap max on packed row v, clamped by k: min(hmax3(v), k)
static __device__ __forceinline__ W8 hpass(W8 v, W8 k) {
    uint32_t lv = dpp_shr1(v.s7);
    uint32_t rv = dpp_shl1(v.s0);
    W8 m;
    m.s0 = pmin(pmax(pmax(v.s0, alignb(v.s0, lv)),   alignb(v.s1, v.s0)), k.s0);
    m.s1 = pmin(pmax(pmax(v.s1, alignb(v.s1, v.s0)), alignb(v.s2, v.s1)), k.s1);
    m.s2 = pmin(pmax(pmax(v.s2, alignb(v.s2, v.s1)), alignb(v.s3, v.s2)), k.s2);
    m.s3 = pmin(pmax(pmax(v.s3, alignb(v.s3, v.s2)), alignb(v.s4, v.s3)), k.s3);
    m.s4 = pmin(pmax(pmax(v.s4, alignb(v.s4, v.s3)), alignb(v.s5, v.s4)), k.s4);
    m.s5 = pmin(pmax(pmax(v.s5, alignb(v.s5, v.s4)), alignb(v.s6, v.s5)), k.s5);
    m.s6 = pmin(pmax(pmax(v.s6, alignb(v.s6, v.s5)), alignb(v.s7, v.s6)), k.s6);
    m.s7 = pmin(pmax(pmax(v.s7, alignb(v.s7, v.s6)), alignb(rv,   v.s7)), k.s7);
    return m;
}

// init: marker = img - h (fp16), maskh = img (fp16). 8 px / thread.
__global__ __launch_bounds__(256) void hx_init(const float* __restrict__ img,
                                               const float* __restrict__ hh,
                                               uint32_t* __restrict__ marker,
                                               uint32_t* __restrict__ maskh) {
    int i = blockIdx.x * 256 + threadIdx.x;
    size_t p0 = (size_t)i * 4;                 // packed index (32768 per image)
    float hb = hh[p0 >> 15];
    const float* src = img + p0 * 2;
    float4 f0 = reinterpret_cast<const float4*>(src)[0];
    float4 f1 = reinterpret_cast<const float4*>(src)[1];
    uint4 km, mk;
    km.x = pack2(f0.x, f0.y);       km.y = pack2(f0.z, f0.w);
    km.z = pack2(f1.x, f1.y);       km.w = pack2(f1.z, f1.w);
    mk.x = pack2(f0.x-hb, f0.y-hb); mk.y = pack2(f0.z-hb, f0.w-hb);
    mk.z = pack2(f1.x-hb, f1.y-hb); mk.w = pack2(f1.z-hb, f1.w-hb);
    *reinterpret_cast<uint4*>(maskh  + p0) = km;
    *reinterpret_cast<uint4*>(marker + p0) = mk;
}

__global__ __launch_bounds__(1024)
__attribute__((amdgpu_waves_per_eu(4, 4)))
void hx_iter(
    const uint32_t* __restrict__ min_,   // marker in (fp16 packed, 128 words/row)
    const uint32_t* __restrict__ maskh,  // mask (fp16 packed)
    uint32_t*       __restrict__ mout,   // marker out (if !final_out)
    float*          __restrict__ fout,   // f32 out (if final_out)
    int final_out)
{
    // [A=0/B=1][row][word]; A row 0 and B row GROUPS are -inf sentinels
    __shared__ uint32_t H[2][GROUPS + 1][LDSS];   // 68,640 B (proven size)

    const int tid  = threadIdx.x;
    const int seg  = tid & 15;
    const int g    = tid >> 4;
    const int b    = blockIdx.x >> 1;
    const int slab = blockIdx.x & 1;
    const int base = slab * 128 - TITER;

    if (tid < LDSS) {            // sentinels (ordered by first loop barrier)
        H[0][0][tid]      = NEGPAIR;
        H[1][GROUPS][tid] = NEGPAIR;
    }

    uint32_t* wrA = &H[0][g + 1][seg * 8]; uint32_t* rdA = &H[0][g][seg * 8];
    uint32_t* wrB = &H[1][g][seg * 8];     uint32_t* rdB = &H[1][g + 1][seg * 8];

    W8 m0, m1, m2, k0, k1, k2;
    {
        int ir = base + 3 * g;
        if (ir >= 0 && ir < 256) {
            size_t rp = (((size_t)(b * 256 + ir)) << 7) + seg * 8;
            m0 = ld8(min_ + rp); k0 = ld8(maskh + rp);
        } else { m0 = wneg(); k0 = wneg(); }
        ir++;
        if (ir >= 0 && ir < 256) {
            size_t rp = (((size_t)(b * 256 + ir)) << 7) + seg * 8;
            m1 = ld8(min_ + rp); k1 = ld8(maskh + rp);
        } else { m1 = wneg(); k1 = wneg(); }
        ir++;
        if (ir >= 0 && ir < 256) {
            size_t rp = (((size_t)(b * 256 + ir)) << 7) + seg * 8;
            m2 = ld8(min_ + rp); k2 = ld8(maskh + rp);
        } else { m2 = wneg(); k2 = wneg(); }
    }

    for (int t = 0; t < TITER; ++t) {
        st8(wrB, m0);
        st8(wrA, m2);
        __syncthreads();
        W8 ab = ld8(rdA);
        W8 bl = ld8(rdB);
        W8 t01 = wmax(m0, m1);
        W8 v1  = wmax(t01, m2);
        W8 nm1 = hpass(v1, k1);               // interior row: no halo dep
        W8 v0  = wmax(ab, t01);
        W8 v2  = wmax(wmax(m1, m2), bl);
        __syncthreads();                      // halo consumed; LDS reusable
        m0 = hpass(v0, k0);
        m2 = hpass(v2, k2);
        m1 = nm1;
    }

    // write back interior rows (local rows [TITER, TITER+128))
    #pragma unroll
    for (int r = 0; r < 3; ++r) {
        int local = 3 * g + r;
        if (local >= TITER && local < TITER + 128) {
            int ir = base + local;
            W8 mv = (r == 0) ? m0 : (r == 1) ? m1 : m2;
            if (final_out) {
                float* orow = fout + (((size_t)(b * 256 + ir)) << 8) + seg * 16;
                h2 x, y; float4 f;
                x = __builtin_bit_cast(h2, mv.s0); y = __builtin_bit_cast(h2, mv.s1);
                f.x = (float)x.x; f.y = (float)x.y; f.z = (float)y.x; f.w = (float)y.y;
                reinterpret_cast<float4*>(orow)[0] = f;
                x = __builtin_bit_cast(h2, mv.s2); y = __builtin_bit_cast(h2, mv.s3);
                f.x = (float)x.x; f.y = (float)x.y; f.z = (float)y.x; f.w = (float)y.y;
                reinterpret_cast<float4*>(orow)[1] = f;
                x = __builtin_bit_cast(h2, mv.s4); y = __builtin_bit_cast(h2, mv.s5);
                f.x = (float)x.x; f.y = (float)x.y; f.z = (float)y.x; f.w = (float)y.y;
                reinterpret_cast<float4*>(orow)[2] = f;
                x = __builtin_bit_cast(h2, mv.s6); y = __builtin_bit_cast(h2, mv.s7);
                f.x = (float)x.x; f.y = (float)x.y; f.z = (float)y.x; f.w = (float)y.y;
                reinterpret_cast<float4*>(orow)[3] = f;
            } else {
                uint32_t* orow = mout + (((size_t)(b * 256 + ir)) << 7) + seg * 8;
                st8(orow, mv);
            }
        }
    }
}

extern "C" void kernel_launch(void* const* d_in, const int* in_sizes, int n_in,
                              void* d_out, int out_size, void* d_ws, size_t ws_size,
                              hipStream_t stream) {
    const float* img = (const float*)d_in[0];
    const float* hh  = (const float*)d_in[1];

    uint32_t* pong  = (uint32_t*)d_ws;           // ws[0 : 16.8MB)
    uint32_t* maskh = pong + 4194304;            // ws[16.8 : 33.5MB)
    uint32_t* ping  = (uint32_t*)d_out;          // first 16.8MB of d_out

    hx_init<<<4096, 256, 0, stream>>>(img, hh, ping, maskh);
    hx_iter<<<256, 1024, 0, stream>>>(ping, maskh, pong, nullptr, 0);
    hx_iter<<<256, 1024, 0, stream>>>(pong, maskh, ping, nullptr, 0);
    hx_iter<<<256, 1024, 0, stream>>>(ping, maskh, pong, nullptr, 0);
    hx_iter<<<256, 1024, 0, stream>>>(pong, maskh, nullptr, (float*)d_out, 1);
}

// Round 15
// 307.957 us; speedup vs baseline: 1.0294x; 1.0294x over previous
//
#include <hip/hip_runtime.h>
#include <stdint.h>

// H-maxima: 128 iters of m = min(dilate3x3(m), img), marker0 = img - h.
// 8 launches x 16 register-resident iterations, fp16 packed (2 px/word).
// Block = 512 threads = 32 groups x 16 segs, thread owns 3 rows x 16 px (W8).
// Slab = 64 useful rows + 16-row halo each side (96 staged); 4 slabs/image;
// grid 512 = 2 blocks/CU -> two independent barrier domains overlap stalls.
// LDS swizzle sw = seg*12 (LDSS=188): b128 8-lane phases hit all 32 banks
// exactly once -> conflict-free. LDS 49.6 KB/block (99.3 KB for 2 blocks/CU).

#define NEGPAIR 0xFBFFFBFFu   // fp16 -65504 x2 == -inf pad
#define TITER 16
#define GROUPS 32
#define LDSS 188              // row stride in words; seg15 span [180,188)

typedef _Float16 h2  __attribute__((ext_vector_type(2)));
typedef __fp16   fh2 __attribute__((ext_vector_type(2)));

static __device__ __forceinline__ uint32_t pmax(uint32_t a, uint32_t b) {
    h2 r = __builtin_elementwise_max(__builtin_bit_cast(h2, a), __builtin_bit_cast(h2, b));
    return __builtin_bit_cast(uint32_t, r);
}
static __device__ __forceinline__ uint32_t pmin(uint32_t a, uint32_t b) {
    h2 r = __builtin_elementwise_min(__builtin_bit_cast(h2, a), __builtin_bit_cast(h2, b));
    return __builtin_bit_cast(uint32_t, r);
}
static __device__ __forceinline__ uint32_t alignb(uint32_t hi, uint32_t lo) {
    return __builtin_amdgcn_alignbit(hi, lo, 16);   // {lo.hi16, hi.lo16}
}
static __device__ __forceinline__ uint32_t pack2(float lo, float hi) {
    fh2 p = __builtin_amdgcn_cvt_pkrtz(lo, hi);
    return __builtin_bit_cast(uint32_t, p);
}
// seg s gets seg s-1's word; seg 0 gets NEGPAIR (16-lane DPP row == seg group)
static __device__ __forceinline__ uint32_t dpp_shr1(uint32_t s) {
    return (uint32_t)__builtin_amdgcn_update_dpp((int)NEGPAIR, (int)s, 0x111, 0xF, 0xF, false);
}
// seg s gets seg s+1's word; seg 15 gets NEGPAIR
static __device__ __forceinline__ uint32_t dpp_shl1(uint32_t s) {
    return (uint32_t)__builtin_amdgcn_update_dpp((int)NEGPAIR, (int)s, 0x101, 0xF, 0xF, false);
}

struct W8 { uint32_t s0, s1, s2, s3, s4, s5, s6, s7; };

static __device__ __forceinline__ W8 ld8(const uint32_t* p) {
    uint4 a = reinterpret_cast<const uint4*>(p)[0];
    uint4 b = reinterpret_cast<const uint4*>(p)[1];
    W8 w;
    w.s0 = a.x; w.s1 = a.y; w.s2 = a.z; w.s3 = a.w;
    w.s4 = b.x; w.s5 = b.y; w.s6 = b.z; w.s7 = b.w;
    return w;
}
static __device__ __forceinline__ void st8(uint32_t* p, W8 w) {
    reinterpret_cast<uint4*>(p)[0] = make_uint4(w.s0, w.s1, w.s2, w.s3);
    reinterpret_cast<uint4*>(p)[1] = make_uint4(w.s4, w.s5, w.s6, w.s7);
}
static __device__ __forceinline__ W8 wmax(W8 a, W8 b) {
    W8 r;
    r.s0 = pmax(a.s0, b.s0); r.s1 = pmax(a.s1, b.s1);
    r.s2 = pmax(a.s2, b.s2); r.s3 = pmax(a.s3, b.s3);
    r.s4 = pmax(a.s4, b.s4); r.s5 = pmax(a.s5, b.s5);
    r.s6 = pmax(a.s6, b.s6); r.s7 = pmax(a.s7, b.s7);
    return r;
}
static __device__ __forceinline__ W8 wneg() {
    W8 r;
    r.s0 = NEGPAIR; r.s1 = NEGPAIR; r.s2 = NEGPAIR; r.s3 = NEGPAIR;
    r.s4 = NEGPAIR; r.s5 = NEGPAIR; r.s6 = NEGPAIR; r.s7 = NEGPAIR;
    return r;
}

// horizontal 3-tap max on packed row v, clamped by k: min(hmax3(v), k)
static __device__ __forceinline__ W8 hpass(W8 v, W8 k) {
    uint32_t lv = dpp_shr1(v.s7);
    uint32_t rv = dpp_shl1(v.s0);
    W8 m;
    m.s0 = pmin(pmax(pmax(v.s0, alignb(v.s0, lv)),   alignb(v.s1, v.s0)), k.s0);
    m.s1 = pmin(pmax(pmax(v.s1, alignb(v.s1, v.s0)), alignb(v.s2, v.s1)), k.s1);
    m.s2 = pmin(pmax(pmax(v.s2, alignb(v.s2, v.s1)), alignb(v.s3, v.s2)), k.s2);
    m.s3 = pmin(pmax(pmax(v.s3, alignb(v.s3, v.s2)), alignb(v.s4, v.s3)), k.s3);
    m.s4 = pmin(pmax(pmax(v.s4, alignb(v.s4, v.s3)), alignb(v.s5, v.s4)), k.s4);
    m.s5 = pmin(pmax(pmax(v.s5, alignb(v.s5, v.s4)), alignb(v.s6, v.s5)), k.s5);
    m.s6 = pmin(pmax(pmax(v.s6, alignb(v.s6, v.s5)), alignb(v.s7, v.s6)), k.s6);
    m.s7 = pmin(pmax(pmax(v.s7, alignb(v.s7, v.s6)), alignb(rv,   v.s7)), k.s7);
    return m;
}

// init: marker = img - h (fp16), maskh = img (fp16). 8 px / thread.
__global__ __launch_bounds__(256) void hx_init(const float* __restrict__ img,
                                               const float* __restrict__ hh,
                                               uint32_t* __restrict__ marker,
                                               uint32_t* __restrict__ maskh) {
    int i = blockIdx.x * 256 + threadIdx.x;
    size_t p0 = (size_t)i * 4;                 // packed index (32768 per image)
    float hb = hh[p0 >> 15];
    const float* src = img + p0 * 2;
    float4 f0 = reinterpret_cast<const float4*>(src)[0];
    float4 f1 = reinterpret_cast<const float4*>(src)[1];
    uint4 km, mk;
    km.x = pack2(f0.x, f0.y);       km.y = pack2(f0.z, f0.w);
    km.z = pack2(f1.x, f1.y);       km.w = pack2(f1.z, f1.w);
    mk.x = pack2(f0.x-hb, f0.y-hb); mk.y = pack2(f0.z-hb, f0.w-hb);
    mk.z = pack2(f1.x-hb, f1.y-hb); mk.w = pack2(f1.z-hb, f1.w-hb);
    *reinterpret_cast<uint4*>(maskh  + p0) = km;
    *reinterpret_cast<uint4*>(marker + p0) = mk;
}

__global__ __launch_bounds__(512, 4) void hx_iter(
    const uint32_t* __restrict__ min_,   // marker in (fp16 packed, 128 words/row)
    const uint32_t* __restrict__ maskh,  // mask (fp16 packed)
    uint32_t*       __restrict__ mout,   // marker out (if !final_out)
    float*          __restrict__ fout,   // f32 out (if final_out)
    int final_out)
{
    // [A=0/B=1][row][word]; A row 0 and B row GROUPS are -inf sentinels
    __shared__ uint32_t H[2][GROUPS + 1][LDSS];   // 49,632 B

    const int tid  = threadIdx.x;
    const int seg  = tid & 15;
    const int g    = tid >> 4;          // 32 groups x 3 rows = 96 staged rows
    const int b    = blockIdx.x >> 2;   // image
    const int slab = blockIdx.x & 3;    // 4 slabs of 64 rows
    const int base = slab * 64 - TITER;
    const int sw   = seg * 12;          // conflict-free, injective, 16B-aligned

    for (int w = tid; w < LDSS; w += 512) {   // sentinels (ordered by 1st barrier)
        H[0][0][w]      = NEGPAIR;
        H[1][GROUPS][w] = NEGPAIR;
    }

    uint32_t* wrA = &H[0][g + 1][sw]; uint32_t* rdA = &H[0][g][sw];
    uint32_t* wrB = &H[1][g][sw];     uint32_t* rdB = &H[1][g + 1][sw];

    W8 m0, m1, m2, k0, k1, k2;
    {
        int ir = base + 3 * g;
        if (ir >= 0 && ir < 256) {
            size_t rp = (((size_t)(b * 256 + ir)) << 7) + seg * 8;
            m0 = ld8(min_ + rp); k0 = ld8(maskh + rp);
        } else { m0 = wneg(); k0 = wneg(); }
        ir++;
        if (ir >= 0 && ir < 256) {
            size_t rp = (((size_t)(b * 256 + ir)) << 7) + seg * 8;
            m1 = ld8(min_ + rp); k1 = ld8(maskh + rp);
        } else { m1 = wneg(); k1 = wneg(); }
        ir++;
        if (ir >= 0 && ir < 256) {
            size_t rp = (((size_t)(b * 256 + ir)) << 7) + seg * 8;
            m2 = ld8(min_ + rp); k2 = ld8(maskh + rp);
        } else { m2 = wneg(); k2 = wneg(); }
    }

    for (int t = 0; t < TITER; ++t) {
        st8(wrB, m0);
        st8(wrA, m2);
        __syncthreads();
        W8 ab = ld8(rdA);
        W8 bl = ld8(rdB);
        W8 t01 = wmax(m0, m1);
        W8 v1  = wmax(t01, m2);
        W8 nm1 = hpass(v1, k1);               // interior row: no halo dep
        W8 v0  = wmax(ab, t01);
        W8 v2  = wmax(wmax(m1, m2), bl);
        __syncthreads();                      // halo consumed; LDS reusable
        m0 = hpass(v0, k0);
        m2 = hpass(v2, k2);
        m1 = nm1;
    }

    // write back useful rows (local rows [TITER, TITER+64))
    #pragma unroll
    for (int r = 0; r < 3; ++r) {
        int local = 3 * g + r;
        if (local >= TITER && local < TITER + 64) {
            int ir = base + local;
            W8 mv = (r == 0) ? m0 : (r == 1) ? m1 : m2;
            if (final_out) {
                float* orow = fout + (((size_t)(b * 256 + ir)) << 8) + seg * 16;
                h2 x, y; float4 f;
                x = __builtin_bit_cast(h2, mv.s0); y = __builtin_bit_cast(h2, mv.s1);
                f.x = (float)x.x; f.y = (float)x.y; f.z = (float)y.x; f.w = (float)y.y;
                reinterpret_cast<float4*>(orow)[0] = f;
                x = __builtin_bit_cast(h2, mv.s2); y = __builtin_bit_cast(h2, mv.s3);
                f.x = (float)x.x; f.y = (float)x.y; f.z = (float)y.x; f.w = (float)y.y;
                reinterpret_cast<float4*>(orow)[1] = f;
                x = __builtin_bit_cast(h2, mv.s4); y = __builtin_bit_cast(h2, mv.s5);
                f.x = (float)x.x; f.y = (float)x.y; f.z = (float)y.x; f.w = (float)y.y;
                reinterpret_cast<float4*>(orow)[2] = f;
                x = __builtin_bit_cast(h2, mv.s6); y = __builtin_bit_cast(h2, mv.s7);
                f.x = (float)x.x; f.y = (float)x.y; f.z = (float)y.x; f.w = (float)y.y;
                reinterpret_cast<float4*>(orow)[3] = f;
            } else {
                uint32_t* orow = mout + (((size_t)(b * 256 + ir)) << 7) + seg * 8;
                st8(orow, mv);
            }
        }
    }
}

extern "C" void kernel_launch(void* const* d_in, const int* in_sizes, int n_in,
                              void* d_out, int out_size, void* d_ws, size_t ws_size,
                              hipStream_t stream) {
    const float* img = (const float*)d_in[0];
    const float* hh  = (const float*)d_in[1];

    uint32_t* pong  = (uint32_t*)d_ws;           // ws[0 : 16.8MB)
    uint32_t* maskh = pong + 4194304;            // ws[16.8 : 33.5MB)
    uint32_t* ping  = (uint32_t*)d_out;          // first 16.8MB of d_out

    hx_init<<<4096, 256, 0, stream>>>(img, hh, ping, maskh);
    // 8 launches x 16 iterations = 128 (even count: ends writing d_out as f32)
    hx_iter<<<512, 512, 0, stream>>>(ping, maskh, pong, nullptr, 0);
    hx_iter<<<512, 512, 0, stream>>>(pong, maskh, ping, nullptr, 0);
    hx_iter<<<512, 512, 0, stream>>>(ping, maskh, pong, nullptr, 0);
    hx_iter<<<512, 512, 0, stream>>>(pong, maskh, ping, nullptr, 0);
    hx_iter<<<512, 512, 0, stream>>>(ping, maskh, pong, nullptr, 0);
    hx_iter<<<512, 512, 0, stream>>>(pong, maskh, ping, nullptr, 0);
    hx_iter<<<512, 512, 0, stream>>>(ping, maskh, pong, nullptr, 0);
    hx_iter<<<512, 512, 0, stream>>>(pong, maskh, nullptr, (float*)d_out, 1);
}

// Round 16
// 255.726 us; speedup vs baseline: 1.2397x; 1.2042x over previous
//
#include <hip/hip_runtime.h>
#include <stdint.h>

// H-maxima: 128 iters of m = min(dilate3x3(m), img), marker0 = img - h.
// 8 launches x 16 register-resident iterations, fp16 packed (2 px/word).
// Block = 512 threads = 32 groups x 16 segs, thread owns 3 rows x 16 px (W8).
// Slab = 64 useful rows + 16-row halo each side; 4 slabs/image; 2 blocks/CU.
// LDS swizzle sw = seg*12 (LDSS=188): conflict-free b128 phases.
// NEW vs R15: pmax/pmin via inline asm v_pk_max_f16/v_pk_min_f16 --
// guarantees 1 VOP3P op each (builtin may lower to 2x scalar SDWA ops,
// the suspected 2.4x VALU bloat that kept per-iter time at 2.7us).

#define NEGPAIR 0xFBFFFBFFu   // fp16 -65504 x2 == -inf pad
#define TITER 16
#define GROUPS 32
#define LDSS 188              // row stride in words; seg15 span [180,188)

typedef _Float16 h2  __attribute__((ext_vector_type(2)));
typedef __fp16   fh2 __attribute__((ext_vector_type(2)));

static __device__ __forceinline__ uint32_t pmax(uint32_t a, uint32_t b) {
    uint32_t r;
    asm("v_pk_max_f16 %0, %1, %2" : "=v"(r) : "v"(a), "v"(b));
    return r;
}
static __device__ __forceinline__ uint32_t pmin(uint32_t a, uint32_t b) {
    uint32_t r;
    asm("v_pk_min_f16 %0, %1, %2" : "=v"(r) : "v"(a), "v"(b));
    return r;
}
static __device__ __forceinline__ uint32_t alignb(uint32_t hi, uint32_t lo) {
    return __builtin_amdgcn_alignbit(hi, lo, 16);   // {lo.hi16, hi.lo16}
}
static __device__ __forceinline__ uint32_t pack2(float lo, float hi) {
    fh2 p = __builtin_amdgcn_cvt_pkrtz(lo, hi);
    return __builtin_bit_cast(uint32_t, p);
}
// seg s gets seg s-1's word; seg 0 gets NEGPAIR (16-lane DPP row == seg group)
static __device__ __forceinline__ uint32_t dpp_shr1(uint32_t s) {
    return (uint32_t)__builtin_amdgcn_update_dpp((int)NEGPAIR, (int)s, 0x111, 0xF, 0xF, false);
}
// seg s gets seg s+1's word; seg 15 gets NEGPAIR
static __device__ __forceinline__ uint32_t dpp_shl1(uint32_t s) {
    return (uint32_t)__builtin_amdgcn_update_dpp((int)NEGPAIR, (int)s, 0x101, 0xF, 0xF, false);
}

struct W8 { uint32_t s0, s1, s2, s3, s4, s5, s6, s7; };

static __device__ __forceinline__ W8 ld8(const uint32_t* p) {
    uint4 a = reinterpret_cast<const uint4*>(p)[0];
    uint4 b = reinterpret_cast<const uint4*>(p)[1];
    W8 w;
    w.s0 = a.x; w.s1 = a.y; w.s2 = a.z; w.s3 = a.w;
    w.s4 = b.x; w.s5 = b.y; w.s6 = b.z; w.s7 = b.w;
    return w;
}
static __device__ __forceinline__ void st8(uint32_t* p, W8 w) {
    reinterpret_cast<uint4*>(p)[0] = make_uint4(w.s0, w.s1, w.s2, w.s3);
    reinterpret_cast<uint4*>(p)[1] = make_uint4(w.s4, w.s5, w.s6, w.s7);
}
static __device__ __forceinline__ W8 wmax(W8 a, W8 b) {
    W8 r;
    r.s0 = pmax(a.s0, b.s0); r.s1 = pmax(a.s1, b.s1);
    r.s2 = pmax(a.s2, b.s2); r.s3 = pmax(a.s3, b.s3);
    r.s4 = pmax(a.s4, b.s4); r.s5 = pmax(a.s5, b.s5);
    r.s6 = pmax(a.s6, b.s6); r.s7 = pmax(a.s7, b.s7);
    return r;
}
static __device__ __forceinline__ W8 wneg() {
    W8 r;
    r.s0 = NEGPAIR; r.s1 = NEGPAIR; r.s2 = NEGPAIR; r.s3 = NEGPAIR;
    r.s4 = NEGPAIR; r.s5 = NEGPAIR; r.s6 = NEGPAIR; r.s7 = NEGPAIR;
    return r;
}

// horizontal 3-tap max on packed row v, clamped by k: min(hmax3(v), k)
static __device__ __forceinline__ W8 hpass(W8 v, W8 k) {
    uint32_t lv = dpp_shr1(v.s7);
    uint32_t rv = dpp_shl1(v.s0);
    W8 m;
    m.s0 = pmin(pmax(pmax(v.s0, alignb(v.s0, lv)),   alignb(v.s1, v.s0)), k.s0);
    m.s1 = pmin(pmax(pmax(v.s1, alignb(v.s1, v.s0)), alignb(v.s2, v.s1)), k.s1);
    m.s2 = pmin(pmax(pmax(v.s2, alignb(v.s2, v.s1)), alignb(v.s3, v.s2)), k.s2);
    m.s3 = pmin(pmax(pmax(v.s3, alignb(v.s3, v.s2)), alignb(v.s4, v.s3)), k.s3);
    m.s4 = pmin(pmax(pmax(v.s4, alignb(v.s4, v.s3)), alignb(v.s5, v.s4)), k.s4);
    m.s5 = pmin(pmax(pmax(v.s5, alignb(v.s5, v.s4)), alignb(v.s6, v.s5)), k.s5);
    m.s6 = pmin(pmax(pmax(v.s6, alignb(v.s6, v.s5)), alignb(v.s7, v.s6)), k.s6);
    m.s7 = pmin(pmax(pmax(v.s7, alignb(v.s7, v.s6)), alignb(rv,   v.s7)), k.s7);
    return m;
}

// init: marker = img - h (fp16), maskh = img (fp16). 8 px / thread.
__global__ __launch_bounds__(256) void hx_init(const float* __restrict__ img,
                                               const float* __restrict__ hh,
                                               uint32_t* __restrict__ marker,
                                               uint32_t* __restrict__ maskh) {
    int i = blockIdx.x * 256 + threadIdx.x;
    size_t p0 = (size_t)i * 4;                 // packed index (32768 per image)
    float hb = hh[p0 >> 15];
    const float* src = img + p0 * 2;
    float4 f0 = reinterpret_cast<const float4*>(src)[0];
    float4 f1 = reinterpret_cast<const float4*>(src)[1];
    uint4 km, mk;
    km.x = pack2(f0.x, f0.y);       km.y = pack2(f0.z, f0.w);
    km.z = pack2(f1.x, f1.y);       km.w = pack2(f1.z, f1.w);
    mk.x = pack2(f0.x-hb, f0.y-hb); mk.y = pack2(f0.z-hb, f0.w-hb);
    mk.z = pack2(f1.x-hb, f1.y-hb); mk.w = pack2(f1.z-hb, f1.w-hb);
    *reinterpret_cast<uint4*>(maskh  + p0) = km;
    *reinterpret_cast<uint4*>(marker + p0) = mk;
}

__global__ __launch_bounds__(512, 4) void hx_iter(
    const uint32_t* __restrict__ min_,   // marker in (fp16 packed, 128 words/row)
    const uint32_t* __restrict__ maskh,  // mask (fp16 packed)
    uint32_t*       __restrict__ mout,   // marker out (if !final_out)
    float*          __restrict__ fout,   // f32 out (if final_out)
    int final_out)
{
    // [A=0/B=1][row][word]; A row 0 and B row GROUPS are -inf sentinels
    __shared__ uint32_t H[2][GROUPS + 1][LDSS];   // 49,632 B

    const int tid  = threadIdx.x;
    const int seg  = tid & 15;
    const int g    = tid >> 4;          // 32 groups x 3 rows = 96 staged rows
    const int b    = blockIdx.x >> 2;   // image
    const int slab = blockIdx.x & 3;    // 4 slabs of 64 rows
    const int base = slab * 64 - TITER;
    const int sw   = seg * 12;          // conflict-free, injective, 16B-aligned

    for (int w = tid; w < LDSS; w += 512) {   // sentinels (ordered by 1st barrier)
        H[0][0][w]      = NEGPAIR;
        H[1][GROUPS][w] = NEGPAIR;
    }

    uint32_t* wrA = &H[0][g + 1][sw]; uint32_t* rdA = &H[0][g][sw];
    uint32_t* wrB = &H[1][g][sw];     uint32_t* rdB = &H[1][g + 1][sw];

    W8 m0, m1, m2, k0, k1, k2;
    {
        int ir = base + 3 * g;
        if (ir >= 0 && ir < 256) {
            size_t rp = (((size_t)(b * 256 + ir)) << 7) + seg * 8;
            m0 = ld8(min_ + rp); k0 = ld8(maskh + rp);
        } else { m0 = wneg(); k0 = wneg(); }
        ir++;
        if (ir >= 0 && ir < 256) {
            size_t rp = (((size_t)(b * 256 + ir)) << 7) + seg * 8;
            m1 = ld8(min_ + rp); k1 = ld8(maskh + rp);
        } else { m1 = wneg(); k1 = wneg(); }
        ir++;
        if (ir >= 0 && ir < 256) {
            size_t rp = (((size_t)(b * 256 + ir)) << 7) + seg * 8;
            m2 = ld8(min_ + rp); k2 = ld8(maskh + rp);
        } else { m2 = wneg(); k2 = wneg(); }
    }

    for (int t = 0; t < TITER; ++t) {
        st8(wrB, m0);
        st8(wrA, m2);
        __syncthreads();
        W8 ab = ld8(rdA);
        W8 bl = ld8(rdB);
        W8 t01 = wmax(m0, m1);
        W8 v1  = wmax(t01, m2);
        W8 nm1 = hpass(v1, k1);               // interior row: no halo dep
        W8 v0  = wmax(ab, t01);
        W8 v2  = wmax(wmax(m1, m2), bl);
        __syncthreads();                      // halo consumed; LDS reusable
        m0 = hpass(v0, k0);
        m2 = hpass(v2, k2);
        m1 = nm1;
    }

    // write back useful rows (local rows [TITER, TITER+64))
    #pragma unroll
    for (int r = 0; r < 3; ++r) {
        int local = 3 * g + r;
        if (local >= TITER && local < TITER + 64) {
            int ir = base + local;
            W8 mv = (r == 0) ? m0 : (r == 1) ? m1 : m2;
            if (final_out) {
                float* orow = fout + (((size_t)(b * 256 + ir)) << 8) + seg * 16;
                h2 x, y; float4 f;
                x = __builtin_bit_cast(h2, mv.s0); y = __builtin_bit_cast(h2, mv.s1);
                f.x = (float)x.x; f.y = (float)x.y; f.z = (float)y.x; f.w = (float)y.y;
                reinterpret_cast<float4*>(orow)[0] = f;
                x = __builtin_bit_cast(h2, mv.s2); y = __builtin_bit_cast(h2, mv.s3);
                f.x = (float)x.x; f.y = (float)x.y; f.z = (float)y.x; f.w = (float)y.y;
                reinterpret_cast<float4*>(orow)[1] = f;
                x = __builtin_bit_cast(h2, mv.s4); y = __builtin_bit_cast(h2, mv.s5);
                f.x = (float)x.x; f.y = (float)x.y; f.z = (float)y.x; f.w = (float)y.y;
                reinterpret_cast<float4*>(orow)[2] = f;
                x = __builtin_bit_cast(h2, mv.s6); y = __builtin_bit_cast(h2, mv.s7);
                f.x = (float)x.x; f.y = (float)x.y; f.z = (float)y.x; f.w = (float)y.y;
                reinterpret_cast<float4*>(orow)[3] = f;
            } else {
                uint32_t* orow = mout + (((size_t)(b * 256 + ir)) << 7) + seg * 8;
                st8(orow, mv);
            }
        }
    }
}

extern "C" void kernel_launch(void* const* d_in, const int* in_sizes, int n_in,
                              void* d_out, int out_size, void* d_ws, size_t ws_size,
                              hipStream_t stream) {
    const float* img = (const float*)d_in[0];
    const float* hh  = (const float*)d_in[1];

    uint32_t* pong  = (uint32_t*)d_ws;           // ws[0 : 16.8MB)
    uint32_t* maskh = pong + 4194304;            // ws[16.8 : 33.5MB)
    uint32_t* ping  = (uint32_t*)d_out;          // first 16.8MB of d_out

    hx_init<<<4096, 256, 0, stream>>>(img, hh, ping, maskh);
    // 8 launches x 16 iterations = 128 (ends writing d_out as f32)
    hx_iter<<<512, 512, 0, stream>>>(ping, maskh, pong, nullptr, 0);
    hx_iter<<<512, 512, 0, stream>>>(pong, maskh, ping, nullptr, 0);
    hx_iter<<<512, 512, 0, stream>>>(ping, maskh, pong, nullptr, 0);
    hx_iter<<<512, 512, 0, stream>>>(pong, maskh, ping, nullptr, 0);
    hx_iter<<<512, 512, 0, stream>>>(ping, maskh, pong, nullptr, 0);
    hx_iter<<<512, 512, 0, stream>>>(pong, maskh, ping, nullptr, 0);
    hx_iter<<<512, 512, 0, stream>>>(ping, maskh, pong, nullptr, 0);
    hx_iter<<<512, 512, 0, stream>>>(pong, maskh, nullptr, (float*)d_out, 1);
}